// Round 6
// baseline (83.385 us; speedup 1.0000x reference)
//
#include <hip/hip_runtime.h>
#include <hip/hip_cooperative_groups.h>
#include <cstdint>
#include <cstddef>

namespace cg = cooperative_groups;

#define NB 20000
#define NT 1000
#define P_PAIRS 50000
#define MARGIN 2.0f
#define RANK_W 0.3f
#define NEG_SENT -1e9f

// ---------------- workspace layout (bytes) ----------------
// [0,        2560000)  label bitmask: uint32 [NB][32]
// [2560000,  2560004)  float sq_total
// [2560004,  2560008)  float rsum
// [2560008,  2560012)  uint  nrp
// [2560012,  2560016)  uint  ticket
// zero range [0, 2560016) = 160001 uint4
// [2560016,  2960016)  float top5[NB][5]
// [2960016,  3040016)  int   numneg[NB]

#define ZERO_U4 160001
#define ZS_BLOCKS 196            // 196*256 = 50176 >= P_PAIRS; <= 256 CUs -> co-resident

// ============ fused zero + scatter (cooperative, 196 blocks) ============
__global__ __launch_bounds__(256)
void zero_scatter_kernel(const int* __restrict__ pb,
                         const int* __restrict__ pt,
                         unsigned int* __restrict__ mask) {
    cg::grid_group grid = cg::this_grid();
    const int tid = blockIdx.x * 256 + threadIdx.x;
    const int n   = gridDim.x * 256;
    uint4* m4 = reinterpret_cast<uint4*>(mask);
    for (int i = tid; i < ZERO_U4; i += n) m4[i] = make_uint4(0u, 0u, 0u, 0u);
    grid.sync();
    if (tid < P_PAIRS) {
        int b = pb[tid];
        int t = pt[tid];
        atomicOr(&mask[b * 32 + (t >> 5)], 1u << (t & 31));
    }
}

// ============ fallback split kernels ============
__global__ void zero_ws_kernel(uint4* __restrict__ ws) {
    int i = blockIdx.x * blockDim.x + threadIdx.x;
    if (i < ZERO_U4) ws[i] = make_uint4(0u, 0u, 0u, 0u);
}

__global__ void scatter_labels_kernel(const int* __restrict__ pb,
                                      const int* __restrict__ pt,
                                      unsigned int* __restrict__ mask) {
    int p = blockIdx.x * blockDim.x + threadIdx.x;
    if (p >= P_PAIRS) return;
    atomicOr(&mask[pb[p] * 32 + (pt[p] >> 5)], 1u << (pt[p] & 31));
}

// branchless sorted-desc insert of x into (t0>=t1>=t2>=t3>=t4)
#define INSERT5(x)                                        \
    {                                                     \
        float _x = (x);                                   \
        float n0 = fmaxf(t0, _x), s0 = fminf(t0, _x);     \
        float n1 = fmaxf(t1, s0), s1 = fminf(t1, s0);     \
        float n2 = fmaxf(t2, s1), s2 = fminf(t2, s1);     \
        float n3 = fmaxf(t3, s2), s3 = fminf(t3, s2);     \
        float n4 = fmaxf(t4, s3);                         \
        t0 = n0; t1 = n1; t2 = n2; t3 = n3; t4 = n4;      \
    }

#define PROC1(xv, lab)                                              \
    {                                                               \
        float _x = (xv);                                            \
        int _lab = (lab);                                           \
        float _s = __builtin_amdgcn_rcpf(1.0f + __expf(-_x));       \
        float _d = (float)_lab - _s;                                \
        sq = fmaf(_d, _d, sq);                                      \
        pcount += _lab;                                             \
        float _xx = _lab ? NEG_SENT : _x;                           \
        INSERT5(_xx);                                               \
    }

#define PROC4(v, bits)                        \
    PROC1((v).x, (int)(((bits) >> 0) & 1u));  \
    PROC1((v).y, (int)(((bits) >> 1) & 1u));  \
    PROC1((v).z, (int)(((bits) >> 2) & 1u));  \
    PROC1((v).w, (int)(((bits) >> 3) & 1u));

// Row kernel v3: 16 lanes/row, 4 rows/wave, 16 rows/block, grid = NB/16 = 1250.
// Loads batched 4-deep per lane for memory-level parallelism.
__global__ __launch_bounds__(256)
void row_kernel(const float* __restrict__ scores,
                const unsigned int* __restrict__ mask,
                float* __restrict__ sq_total,
                float* __restrict__ top5,
                int* __restrict__ numneg) {
    const int lane = threadIdx.x & 63;
    const int wib  = threadIdx.x >> 6;      // wave in block 0..3
    const int grp  = lane >> 4;             // group in wave  0..3
    const int gl   = lane & 15;             // lane in group  0..15
    const int row  = blockIdx.x * 16 + wib * 4 + grp;

    const float4* rowp = reinterpret_cast<const float4*>(scores + (size_t)row * NT);
    const unsigned int* mrow = mask + row * 32;
    const int wb = gl >> 3;                 // mask word base (0/1)
    const int sh = (gl & 7) * 4;            // nibble shift, constant per lane

    float t0 = NEG_SENT, t1 = NEG_SENT, t2 = NEG_SENT, t3 = NEG_SENT, t4 = NEG_SENT;
    float sq = 0.0f;
    int pcount = 0;

    // i = gl + 16k, k = 0..15 (k=15 only for gl<10; 250 float4 per row)
    // mask word index = wb + 2k; nibble shift = sh (constant)
#define BATCH4(k0)                                                   \
    {                                                                \
        float4 va = rowp[gl + 16 * ((k0) + 0)];                      \
        float4 vb = rowp[gl + 16 * ((k0) + 1)];                      \
        float4 vc = rowp[gl + 16 * ((k0) + 2)];                      \
        float4 vd = rowp[gl + 16 * ((k0) + 3)];                      \
        unsigned int ba = (mrow[wb + 2 * ((k0) + 0)] >> sh) & 0xFu;  \
        unsigned int bbb = (mrow[wb + 2 * ((k0) + 1)] >> sh) & 0xFu; \
        unsigned int bc = (mrow[wb + 2 * ((k0) + 2)] >> sh) & 0xFu;  \
        unsigned int bd = (mrow[wb + 2 * ((k0) + 3)] >> sh) & 0xFu;  \
        PROC4(va, ba); PROC4(vb, bbb); PROC4(vc, bc); PROC4(vd, bd); \
    }

    BATCH4(0);
    BATCH4(4);
    BATCH4(8);
    {   // k = 12..14 (uniform for all lanes)
        float4 va = rowp[gl + 192];
        float4 vb = rowp[gl + 208];
        float4 vc = rowp[gl + 224];
        unsigned int ba = (mrow[wb + 24] >> sh) & 0xFu;
        unsigned int bbb = (mrow[wb + 26] >> sh) & 0xFu;
        unsigned int bc = (mrow[wb + 28] >> sh) & 0xFu;
        PROC4(va, ba); PROC4(vb, bbb); PROC4(vc, bc);
    }
    if (gl < 10) {   // k = 15 tail: i = gl + 240 < 250 only for gl<10
        float4 v = rowp[gl + 240];
        unsigned int bt = (mrow[wb + 30] >> sh) & 0xFu;
        PROC4(v, bt);
    }

    // 4 xor-rounds within each 16-lane group: merge sorted-5 + reduce sq/pcount
    #pragma unroll
    for (int off = 8; off >= 1; off >>= 1) {
        float b0 = __shfl_xor(t0, off, 16);
        float b1 = __shfl_xor(t1, off, 16);
        float b2 = __shfl_xor(t2, off, 16);
        float b3 = __shfl_xor(t3, off, 16);
        float b4 = __shfl_xor(t4, off, 16);
        sq     += __shfl_xor(sq, off, 16);
        pcount += __shfl_xor(pcount, off, 16);

        float m1  = fminf(t0, b0);
        float m2a = fminf(t1, b0), m2b = fminf(t0, b1);
        float m3a = fminf(t2, b0), m3b = fminf(t1, b1), m3c = fminf(t0, b2);
        float m4a = fminf(t3, b0), m4b = fminf(t2, b1), m4c = fminf(t1, b2), m4d = fminf(t0, b3);
        float c0 = fmaxf(t0, b0);
        float c1 = fmaxf(fmaxf(t1, b1), m1);
        float c2 = fmaxf(fmaxf(t2, b2), fmaxf(m2a, m2b));
        float c3 = fmaxf(fmaxf(t3, b3), fmaxf(fmaxf(m3a, m3b), m3c));
        float c4 = fmaxf(fmaxf(t4, b4), fmaxf(fmaxf(m4a, m4b), fmaxf(m4c, m4d)));
        t0 = c0; t1 = c1; t2 = c2; t3 = c3; t4 = c4;
    }

    if (gl == 0) {
        float* tp = top5 + (size_t)row * 5;
        tp[0] = t0; tp[1] = t1; tp[2] = t2; tp[3] = t3; tp[4] = t4;
        numneg[row] = NT - pcount;
    }

    __shared__ float bsq[16];
    if (gl == 0) bsq[(threadIdx.x >> 4)] = sq;
    __syncthreads();
    if (threadIdx.x == 0) {
        float s = 0.0f;
        #pragma unroll
        for (int k = 0; k < 16; ++k) s += bsq[k];
        atomicAdd(sq_total, s);
    }
}

// pair contributions + last-block finalize (ticket pattern)
__global__ __launch_bounds__(256)
void pair_finalize_kernel(const float* __restrict__ scores,
                          const int* __restrict__ pb,
                          const int* __restrict__ pt,
                          const float* __restrict__ top5,
                          const int* __restrict__ numneg,
                          float* __restrict__ sq_total,
                          float* __restrict__ rsum,
                          unsigned int* __restrict__ nrp,
                          unsigned int* __restrict__ ticket,
                          float* __restrict__ out) {
    int p = blockIdx.x * blockDim.x + threadIdx.x;
    float c = 0.0f;
    unsigned int valid = 0;
    if (p < P_PAIRS) {
        int b = pb[p];
        int t = pt[p];
        float pos = scores[(size_t)b * NT + t];
        const float* tp = top5 + (size_t)b * 5;
        #pragma unroll
        for (int k = 0; k < 5; ++k) {
            float contrib = MARGIN - (pos - tp[k]);
            c += contrib > 0.0f ? contrib : 0.0f;
        }
        int nn = numneg[b];
        valid = (unsigned int)(nn < 5 ? nn : 5);
    }
    #pragma unroll
    for (int off = 32; off >= 1; off >>= 1) {
        c     += __shfl_xor(c, off);
        valid += __shfl_xor(valid, off);
    }
    __shared__ float sc[4];
    __shared__ unsigned int sv[4];
    const int wib = threadIdx.x >> 6;
    if ((threadIdx.x & 63) == 0) { sc[wib] = c; sv[wib] = valid; }
    __syncthreads();
    if (threadIdx.x == 0) {
        atomicAdd(rsum, sc[0] + sc[1] + sc[2] + sc[3]);
        atomicAdd(nrp,  sv[0] + sv[1] + sv[2] + sv[3]);
        __threadfence();
        unsigned int done = atomicAdd(ticket, 1u);
        if (done == gridDim.x - 1) {
            float sqt = atomicAdd(sq_total, 0.0f);
            float rs  = atomicAdd(rsum, 0.0f);
            unsigned int n = atomicAdd(nrp, 0u);
            float loss = 0.5f * sqt / 2.0e7f;        // NB*NT = 2e7
            if (n > 0) loss += RANK_W * rs / (float)n;
            out[0] = loss;
        }
    }
}

extern "C" void kernel_launch(void* const* d_in, const int* in_sizes, int n_in,
                              void* d_out, int out_size, void* d_ws, size_t ws_size,
                              hipStream_t stream) {
    const float* scores = (const float*)d_in[0];
    const int*   pb     = (const int*)d_in[1];
    const int*   pt     = (const int*)d_in[2];
    float*       out    = (float*)d_out;

    char* ws = (char*)d_ws;
    unsigned int* mask     = (unsigned int*)ws;
    float*        sq_total = (float*)(ws + 2560000);
    float*        rsum     = (float*)(ws + 2560004);
    unsigned int* nrp      = (unsigned int*)(ws + 2560008);
    unsigned int* ticket   = (unsigned int*)(ws + 2560012);
    float*        top5     = (float*)(ws + 2560016);
    int*          numneg   = (int*)(ws + 2960016);

    // fused zero+scatter: 196 blocks (co-resident; grid.sync valid)
    void* zs_args[] = {(void*)&pb, (void*)&pt, (void*)&mask};
    hipError_t lerr = hipLaunchCooperativeKernel((const void*)zero_scatter_kernel,
                                                 dim3(ZS_BLOCKS), dim3(256),
                                                 zs_args, 0, stream);
    if (lerr != hipSuccess) {
        zero_ws_kernel<<<(ZERO_U4 + 255) / 256, 256, 0, stream>>>((uint4*)ws);
        scatter_labels_kernel<<<(P_PAIRS + 255) / 256, 256, 0, stream>>>(pb, pt, mask);
    }

    row_kernel<<<NB / 16, 256, 0, stream>>>(scores, mask, sq_total, top5, numneg);
    pair_finalize_kernel<<<(P_PAIRS + 255) / 256, 256, 0, stream>>>(
        scores, pb, pt, top5, numneg, sq_total, rsum, nrp, ticket, out);
}

// Round 7
// 50.229 us; speedup vs baseline: 1.6601x; 1.6601x over previous
//
#include <hip/hip_runtime.h>
#include <cstdint>
#include <cstddef>

#define NB 20000
#define NT 1000
#define P_PAIRS 50000
#define MARGIN 2.0f
#define RANK_W 0.3f
#define NEG_SENT -1e9f

// ---------------- workspace layout (bytes) ----------------
// [0,        2560000)  label bitmask: uint32 [NB][32]
// [2560000,  2560004)  float sq_total
// [2560004,  2560008)  float rsum
// [2560008,  2560012)  uint  nrp
// [2560012,  2560016)  uint  ticket
// zero range [0, 2560016) = 160001 uint4
// [2560016,  2960016)  float top5[NB][5]
// [2960016,  3040016)  int   numneg[NB]

#define ZERO_U4 160001

__global__ void zero_ws_kernel(uint4* __restrict__ ws) {
    int i = blockIdx.x * blockDim.x + threadIdx.x;
    if (i < ZERO_U4) ws[i] = make_uint4(0u, 0u, 0u, 0u);
}

__global__ void scatter_labels_kernel(const int* __restrict__ pb,
                                      const int* __restrict__ pt,
                                      unsigned int* __restrict__ mask) {
    int p = blockIdx.x * blockDim.x + threadIdx.x;
    if (p >= P_PAIRS) return;
    atomicOr(&mask[pb[p] * 32 + (pt[p] >> 5)], 1u << (pt[p] & 31));
}

// branchless sorted-desc insert of x into (t0>=t1>=t2>=t3>=t4)
#define INSERT5(x)                                        \
    {                                                     \
        float _x = (x);                                   \
        float n0 = fmaxf(t0, _x), s0 = fminf(t0, _x);     \
        float n1 = fmaxf(t1, s0), s1 = fminf(t1, s0);     \
        float n2 = fmaxf(t2, s1), s2 = fminf(t2, s1);     \
        float n3 = fmaxf(t3, s2), s3 = fminf(t3, s2);     \
        float n4 = fmaxf(t4, s3);                         \
        t0 = n0; t1 = n1; t2 = n2; t3 = n3; t4 = n4;      \
    }

#define PROC1(xv, lab)                                              \
    {                                                               \
        float _x = (xv);                                            \
        int _lab = (lab);                                           \
        float _s = __builtin_amdgcn_rcpf(1.0f + __expf(-_x));       \
        float _d = (float)_lab - _s;                                \
        sq = fmaf(_d, _d, sq);                                      \
        pcount += _lab;                                             \
        float _xx = _lab ? NEG_SENT : _x;                           \
        INSERT5(_xx);                                               \
    }

#define PROC4(v, bits)                        \
    PROC1((v).x, (int)(((bits) >> 0) & 1u));  \
    PROC1((v).y, (int)(((bits) >> 1) & 1u));  \
    PROC1((v).z, (int)(((bits) >> 2) & 1u));  \
    PROC1((v).w, (int)(((bits) >> 3) & 1u));

// Row kernel v3: 16 lanes/row, 4 rows/wave, 16 rows/block, grid = NB/16 = 1250.
// Loads batched 4-deep per lane for memory-level parallelism.
__global__ __launch_bounds__(256)
void row_kernel(const float* __restrict__ scores,
                const unsigned int* __restrict__ mask,
                float* __restrict__ sq_total,
                float* __restrict__ top5,
                int* __restrict__ numneg) {
    const int lane = threadIdx.x & 63;
    const int wib  = threadIdx.x >> 6;      // wave in block 0..3
    const int grp  = lane >> 4;             // group in wave  0..3
    const int gl   = lane & 15;             // lane in group  0..15
    const int row  = blockIdx.x * 16 + wib * 4 + grp;

    const float4* rowp = reinterpret_cast<const float4*>(scores + (size_t)row * NT);
    const unsigned int* mrow = mask + row * 32;
    const int wb = gl >> 3;                 // mask word base (0/1)
    const int sh = (gl & 7) * 4;            // nibble shift, constant per lane

    float t0 = NEG_SENT, t1 = NEG_SENT, t2 = NEG_SENT, t3 = NEG_SENT, t4 = NEG_SENT;
    float sq = 0.0f;
    int pcount = 0;

    // i = gl + 16k, k = 0..15 (k=15 only for gl<10; 250 float4 per row)
    // mask word index = wb + 2k; nibble shift = sh (constant per lane)
#define BATCH4(k0)                                                   \
    {                                                                \
        float4 va = rowp[gl + 16 * ((k0) + 0)];                      \
        float4 vb = rowp[gl + 16 * ((k0) + 1)];                      \
        float4 vc = rowp[gl + 16 * ((k0) + 2)];                      \
        float4 vd = rowp[gl + 16 * ((k0) + 3)];                      \
        unsigned int ba = (mrow[wb + 2 * ((k0) + 0)] >> sh) & 0xFu;  \
        unsigned int bbb = (mrow[wb + 2 * ((k0) + 1)] >> sh) & 0xFu; \
        unsigned int bc = (mrow[wb + 2 * ((k0) + 2)] >> sh) & 0xFu;  \
        unsigned int bd = (mrow[wb + 2 * ((k0) + 3)] >> sh) & 0xFu;  \
        PROC4(va, ba); PROC4(vb, bbb); PROC4(vc, bc); PROC4(vd, bd); \
    }

    BATCH4(0);
    BATCH4(4);
    BATCH4(8);
    {   // k = 12..14 (uniform for all lanes)
        float4 va = rowp[gl + 192];
        float4 vb = rowp[gl + 208];
        float4 vc = rowp[gl + 224];
        unsigned int ba = (mrow[wb + 24] >> sh) & 0xFu;
        unsigned int bbb = (mrow[wb + 26] >> sh) & 0xFu;
        unsigned int bc = (mrow[wb + 28] >> sh) & 0xFu;
        PROC4(va, ba); PROC4(vb, bbb); PROC4(vc, bc);
    }
    if (gl < 10) {   // k = 15 tail: i = gl + 240 < 250 only for gl<10
        float4 v = rowp[gl + 240];
        unsigned int bt = (mrow[wb + 30] >> sh) & 0xFu;
        PROC4(v, bt);
    }

    // 4 xor-rounds within each 16-lane group: merge sorted-5 + reduce sq/pcount
    #pragma unroll
    for (int off = 8; off >= 1; off >>= 1) {
        float b0 = __shfl_xor(t0, off, 16);
        float b1 = __shfl_xor(t1, off, 16);
        float b2 = __shfl_xor(t2, off, 16);
        float b3 = __shfl_xor(t3, off, 16);
        float b4 = __shfl_xor(t4, off, 16);
        sq     += __shfl_xor(sq, off, 16);
        pcount += __shfl_xor(pcount, off, 16);

        float m1  = fminf(t0, b0);
        float m2a = fminf(t1, b0), m2b = fminf(t0, b1);
        float m3a = fminf(t2, b0), m3b = fminf(t1, b1), m3c = fminf(t0, b2);
        float m4a = fminf(t3, b0), m4b = fminf(t2, b1), m4c = fminf(t1, b2), m4d = fminf(t0, b3);
        float c0 = fmaxf(t0, b0);
        float c1 = fmaxf(fmaxf(t1, b1), m1);
        float c2 = fmaxf(fmaxf(t2, b2), fmaxf(m2a, m2b));
        float c3 = fmaxf(fmaxf(t3, b3), fmaxf(fmaxf(m3a, m3b), m3c));
        float c4 = fmaxf(fmaxf(t4, b4), fmaxf(fmaxf(m4a, m4b), fmaxf(m4c, m4d)));
        t0 = c0; t1 = c1; t2 = c2; t3 = c3; t4 = c4;
    }

    if (gl == 0) {
        float* tp = top5 + (size_t)row * 5;
        tp[0] = t0; tp[1] = t1; tp[2] = t2; tp[3] = t3; tp[4] = t4;
        numneg[row] = NT - pcount;
    }

    __shared__ float bsq[16];
    if (gl == 0) bsq[(threadIdx.x >> 4)] = sq;
    __syncthreads();
    if (threadIdx.x == 0) {
        float s = 0.0f;
        #pragma unroll
        for (int k = 0; k < 16; ++k) s += bsq[k];
        atomicAdd(sq_total, s);
    }
}

// pair contributions + last-block finalize (ticket pattern)
__global__ __launch_bounds__(256)
void pair_finalize_kernel(const float* __restrict__ scores,
                          const int* __restrict__ pb,
                          const int* __restrict__ pt,
                          const float* __restrict__ top5,
                          const int* __restrict__ numneg,
                          float* __restrict__ sq_total,
                          float* __restrict__ rsum,
                          unsigned int* __restrict__ nrp,
                          unsigned int* __restrict__ ticket,
                          float* __restrict__ out) {
    int p = blockIdx.x * blockDim.x + threadIdx.x;
    float c = 0.0f;
    unsigned int valid = 0;
    if (p < P_PAIRS) {
        int b = pb[p];
        int t = pt[p];
        float pos = scores[(size_t)b * NT + t];
        const float* tp = top5 + (size_t)b * 5;
        #pragma unroll
        for (int k = 0; k < 5; ++k) {
            float contrib = MARGIN - (pos - tp[k]);
            c += contrib > 0.0f ? contrib : 0.0f;
        }
        int nn = numneg[b];
        valid = (unsigned int)(nn < 5 ? nn : 5);
    }
    #pragma unroll
    for (int off = 32; off >= 1; off >>= 1) {
        c     += __shfl_xor(c, off);
        valid += __shfl_xor(valid, off);
    }
    __shared__ float sc[4];
    __shared__ unsigned int sv[4];
    const int wib = threadIdx.x >> 6;
    if ((threadIdx.x & 63) == 0) { sc[wib] = c; sv[wib] = valid; }
    __syncthreads();
    if (threadIdx.x == 0) {
        atomicAdd(rsum, sc[0] + sc[1] + sc[2] + sc[3]);
        atomicAdd(nrp,  sv[0] + sv[1] + sv[2] + sv[3]);
        __threadfence();
        unsigned int done = atomicAdd(ticket, 1u);
        if (done == gridDim.x - 1) {
            float sqt = atomicAdd(sq_total, 0.0f);
            float rs  = atomicAdd(rsum, 0.0f);
            unsigned int n = atomicAdd(nrp, 0u);
            float loss = 0.5f * sqt / 2.0e7f;        // NB*NT = 2e7
            if (n > 0) loss += RANK_W * rs / (float)n;
            out[0] = loss;
        }
    }
}

extern "C" void kernel_launch(void* const* d_in, const int* in_sizes, int n_in,
                              void* d_out, int out_size, void* d_ws, size_t ws_size,
                              hipStream_t stream) {
    const float* scores = (const float*)d_in[0];
    const int*   pb     = (const int*)d_in[1];
    const int*   pt     = (const int*)d_in[2];
    float*       out    = (float*)d_out;

    char* ws = (char*)d_ws;
    unsigned int* mask     = (unsigned int*)ws;
    float*        sq_total = (float*)(ws + 2560000);
    float*        rsum     = (float*)(ws + 2560004);
    unsigned int* nrp      = (unsigned int*)(ws + 2560008);
    unsigned int* ticket   = (unsigned int*)(ws + 2560012);
    float*        top5     = (float*)(ws + 2560016);
    int*          numneg   = (int*)(ws + 2960016);

    zero_ws_kernel<<<(ZERO_U4 + 255) / 256, 256, 0, stream>>>((uint4*)ws);
    scatter_labels_kernel<<<(P_PAIRS + 255) / 256, 256, 0, stream>>>(pb, pt, mask);
    row_kernel<<<NB / 16, 256, 0, stream>>>(scores, mask, sq_total, top5, numneg);
    pair_finalize_kernel<<<(P_PAIRS + 255) / 256, 256, 0, stream>>>(
        scores, pb, pt, top5, numneg, sq_total, rsum, nrp, ticket, out);
}